// Round 4
// baseline (15139.075 us; speedup 1.0000x reference)
//
#include <hip/hip_runtime.h>
#include <math.h>

#define S_LEN 4096
#define HID   2048
#define NBLK  256
#define NTHR  512   // 8 waves/block, 1 block/CU

typedef unsigned int       u32;
typedef unsigned long long u64;

// R8 = R7 skeleton with the weights stashed in AGPRs.
//  Three rounds of evidence (VGPR_Count 112/104/96 < 128) show the VGPR
//  allocator refuses to keep 128 loop-spanning weight values resident: it
//  either re-fetches from global (R4/R6) or spills to scratch (R7), costing
//  ~256 KB/CU/step of L2/MALL traffic (~1.7 us of the 2.84 us step).
//  Fix: force the weights into AGPR-class values (`"=a"` constraints,
//  v_accvgpr_write_b32 at init, v_accvgpr_read_b32 at the single use per
//  step). AGPRs are the allocator's last-resort spill class; 128 AGPR +
//  ~70 VGPR fits the 256/wave budget at unchanged occupancy. The volatile
//  writes also pin the global loads before the loop.
//  Kept from R7 (validated): 4B tag-in-mantissa entries (tag = 2 LSBs,
//  cycle {1,3}/{0,2}; 0xAA poison &3==2 only aliases buf1's t=3 tag,
//  overwritten at t=1), paired u64 tight polls, coalesced 32B publish from
//  the 8-lane tail, exp2 sigmoid/tanh, setprio(1) around the tail.

__device__ __forceinline__ float fast_sigmoid(float x) {
    float e = __builtin_amdgcn_exp2f(-1.44269504f * x);   // 2^(-x*log2e)
    return __builtin_amdgcn_rcpf(1.0f + e);
}

__global__ __launch_bounds__(NTHR, 2)
void qlstm_persistent(const float* __restrict__ inp,     // (S,1,4)
                      const float* __restrict__ conv_w,  // (4)
                      const float* __restrict__ conv_b,  // (1)
                      const float* __restrict__ Wg,      // (2049, 8192) row-major
                      const float* __restrict__ bg,      // (8192)
                      float* __restrict__ out,           // S*H + H + H
                      float* __restrict__ ws)            // scratch (poison 0xAA ok)
{
    const int b   = blockIdx.x;
    const int tid = threadIdx.x;
    const int l   = tid & 63;
    const int wv  = tid >> 6;

    u32* tb0 = (u32*)ws;            // [HID] tagged hx, parity 0 (holds even t)
    u32* tb1 = tb0 + HID + 16;      // [HID] tagged hx, parity 1 (line-padded)

    __shared__ __align__(16) float hx_lds[HID];
    __shared__ __align__(16) float conv_lds[S_LEN];
    __shared__ float gates_lds[32];
    __shared__ float colw0[32];
    __shared__ float colb[32];

    // ---------------- init phase ----------------
    {
        const float cw0 = conv_w[0], cw1 = conv_w[1], cw2 = conv_w[2], cw3 = conv_w[3];
        const float cb  = conv_b[0];
        for (int g = tid; g < S_LEN; g += NTHR) {
            float4 x = ((const float4*)inp)[g];
            float v = x.x*cw0 + x.y*cw1 + x.z*cw2 + x.w*cw3 + cb;
            conv_lds[g] = fast_sigmoid(v);
        }
    }
    // hx_0 = 0 lives purely in LDS: step 0 needs no global exchange at all.
    ((float4*)hx_lds)[tid] = make_float4(0.f, 0.f, 0.f, 0.f);

    // this wave's 4 global column indices
    int jcol[4];
    #pragma unroll
    for (int c = 0; c < 4; ++c) {
        int cgi  = 4*wv + c;
        int gate = cgi >> 3;
        int mi   = cgi & 7;
        jcol[c]  = (gate << 11) + (b * 8 + mi);     // gate*2048 + m
    }
    if (l == 0) {
        #pragma unroll
        for (int c = 0; c < 4; ++c) {
            int cgi = 4*wv + c;
            colw0[cgi] = Wg[jcol[c]];               // row 0 = input (c_t) weight
            colb[cgi]  = bg[jcol[c]];
        }
    }

    // Load W[1 + 4l + 256j + r][jcol[c]] and stash each value in an AGPR.
    // The volatile v_accvgpr_write pins the load before the loop; the value
    // then lives in AGPR class, which the allocator does not spill (128 AGPR
    // + small VGPR working set fits the 256/wave unified budget).
    float wa[4][32];
    #pragma unroll
    for (int j = 0; j < 8; ++j)
        #pragma unroll
        for (int r = 0; r < 4; ++r) {
            const float* rowp = Wg + (size_t)(1 + 4*l + 256*j + r) * 8192;
            #pragma unroll
            for (int c = 0; c < 4; ++c) {
                float tmp = rowp[jcol[c]];
                asm volatile("v_accvgpr_write_b32 %0, %1"
                             : "=a"(wa[c][4*j + r]) : "v"(tmp));
            }
        }

    float cx = 0.0f;                    // live only in lanes tid<8
    const int m_out = b * 8 + tid;      // hidden index for tid<8
    const int e0 = tid * 4;             // this thread's contiguous 4-entry span

    u32 v0 = 0, v1 = 0, v2 = 0, v3 = 0;
    unsigned pend = 0;                  // t=0 needs nothing (hx_0 zeros pre-staged)

    // ---------------- recurrence ----------------
    for (int t = 0; t < S_LEN; ++t) {
        u32* tb = (t & 1) ? tb1 : tb0;  // hx_t lives here, tag ((t+1)&3)^2
        u32* tn = (t & 1) ? tb0 : tb1;  // hx_{t+1} goes here, tag ((t+2)&3)^2

        if (pend) {
            const u32 want = ((u32)(t + 1) & 3u) ^ 2u;
            do {
                u64 qa = 0, qb = 0;
                if (pend & 3u)
                    qa = __hip_atomic_load((const u64*)(tb + e0),
                                           __ATOMIC_RELAXED, __HIP_MEMORY_SCOPE_AGENT);
                if (pend & 12u)
                    qb = __hip_atomic_load((const u64*)(tb + e0 + 2),
                                           __ATOMIC_RELAXED, __HIP_MEMORY_SCOPE_AGENT);
                u32 c0 = (u32)qa, c1 = (u32)(qa >> 32);
                u32 c2 = (u32)qb, c3 = (u32)(qb >> 32);
                if ((pend & 1u) && (c0 & 3u) == want) { v0 = c0; pend &= ~1u; }
                if ((pend & 2u) && (c1 & 3u) == want) { v1 = c1; pend &= ~2u; }
                if ((pend & 4u) && (c2 & 3u) == want) { v2 = c2; pend &= ~4u; }
                if ((pend & 8u) && (c3 & 3u) == want) { v3 = c3; pend &= ~8u; }
            } while (pend);
            uint4 st;
            st.x = v0 & ~3u; st.y = v1 & ~3u; st.z = v2 & ~3u; st.w = v3 & ~3u;
            ((uint4*)hx_lds)[tid] = st;     // ds_write_b128, conflict-free
        }
        __syncthreads();                    // A: hx_t staged

        // ---- 2048-MAC dot for this wave's 4 gate columns ----
        // weights come back from AGPRs: 1 v_accvgpr_read per FMA, no memory.
        const float4* hl = (const float4*)hx_lds;
        float acc0 = 0.f, acc1 = 0.f, acc2 = 0.f, acc3 = 0.f;
        #pragma unroll
        for (int j = 0; j < 8; ++j) {
            float4 h = hl[l + 64*j];        // ds_read_b128, conflict-free
            #pragma unroll
            for (int r = 0; r < 4; ++r) {
                float hr = (r == 0) ? h.x : (r == 1) ? h.y : (r == 2) ? h.z : h.w;
                float w0_, w1_, w2_, w3_;
                asm("v_accvgpr_read_b32 %0, %1" : "=v"(w0_) : "a"(wa[0][4*j + r]));
                asm("v_accvgpr_read_b32 %0, %1" : "=v"(w1_) : "a"(wa[1][4*j + r]));
                asm("v_accvgpr_read_b32 %0, %1" : "=v"(w2_) : "a"(wa[2][4*j + r]));
                asm("v_accvgpr_read_b32 %0, %1" : "=v"(w3_) : "a"(wa[3][4*j + r]));
                acc0 = fmaf(hr, w0_, acc0);
                acc1 = fmaf(hr, w1_, acc1);
                acc2 = fmaf(hr, w2_, acc2);
                acc3 = fmaf(hr, w3_, acc3);
            }
        }
        #pragma unroll
        for (int off = 32; off; off >>= 1) {
            acc0 += __shfl_down(acc0, off, 64);
            acc1 += __shfl_down(acc1, off, 64);
            acc2 += __shfl_down(acc2, off, 64);
            acc3 += __shfl_down(acc3, off, 64);
        }
        if (l == 0) {
            gates_lds[4*wv + 0] = acc0;
            gates_lds[4*wv + 1] = acc1;
            gates_lds[4*wv + 2] = acc2;
            gates_lds[4*wv + 3] = acc3;
        }
        __syncthreads();                    // B: gates complete

        if (wv == 0) __builtin_amdgcn_s_setprio(1);   // publisher outranks spinners
        if (tid < 8) {
            float ct = conv_lds[t];
            float fg = gates_lds[tid]      + ct*colw0[tid]      + colb[tid];
            float ig = gates_lds[8 + tid]  + ct*colw0[8 + tid]  + colb[8 + tid];
            float gg = gates_lds[16 + tid] + ct*colw0[16 + tid] + colb[16 + tid];
            float og = gates_lds[24 + tid] + ct*colw0[24 + tid] + colb[24 + tid];
            float f  = fast_sigmoid(fg);
            float ii = fast_sigmoid(ig);
            float gv = 2.0f * fast_sigmoid(2.0f * gg) - 1.0f;   // tanh
            float o  = fast_sigmoid(og);
            cx = f * cx + ii * gv;
            float hx = o * (2.0f * fast_sigmoid(2.0f * cx) - 1.0f);
            // publish: value with tag ((t+2)&3)^2 in the 2 mantissa LSBs.
            // 8 lanes of wave 0 -> one coalesced 32B store (single request).
            u32 word = (__float_as_uint(hx) & ~3u) | (((u32)(t + 2) & 3u) ^ 2u);
            __hip_atomic_store(&tn[m_out], word,
                               __ATOMIC_RELAXED, __HIP_MEMORY_SCOPE_AGENT);
            out[(size_t)t * HID + m_out] = hx;
            if (t == S_LEN - 1) {
                out[(size_t)S_LEN * HID + m_out]       = hx;   // final hx
                out[(size_t)S_LEN * HID + HID + m_out] = cx;   // final cx
            }
        }
        if (wv == 0) __builtin_amdgcn_s_setprio(0);

        pend = 0xFu;
    }
}

extern "C" void kernel_launch(void* const* d_in, const int* in_sizes, int n_in,
                              void* d_out, int out_size, void* d_ws, size_t ws_size,
                              hipStream_t stream) {
    const float* inp    = (const float*)d_in[0];
    const float* conv_w = (const float*)d_in[1];
    const float* conv_b = (const float*)d_in[2];
    const float* Wg     = (const float*)d_in[3];
    const float* bg     = (const float*)d_in[4];
    float* out = (float*)d_out;
    float* ws  = (float*)d_ws;

    // no memset needed: tag cycle {1,3}/{0,2} — poison (&3==2) only aliases
    // buf1's t=3 tag, and every buf1 entry is overwritten at t=1 first.
    void* args[] = {(void*)&inp, (void*)&conv_w, (void*)&conv_b,
                    (void*)&Wg, (void*)&bg, (void*)&out, (void*)&ws};
    hipLaunchCooperativeKernel((void*)qlstm_persistent,
                               dim3(NBLK), dim3(NTHR), args, 0, stream);
}

// Round 5
// 11453.336 us; speedup vs baseline: 1.3218x; 1.3218x over previous
//
#include <hip/hip_runtime.h>
#include <math.h>

#define S_LEN 4096
#define HID   2048
#define NBLK  256
#define NTHR  512   // 8 waves/block, 1 block/CU

typedef unsigned int       u32;
typedef unsigned long long u64;
typedef unsigned u32x4 __attribute__((ext_vector_type(4)));

// R9: kill publish false-sharing + cut poll request rate. Evidence trail:
//  - R8 (AGPR-resident weights) was SLOWER than R7 despite FETCH -148MB:
//    weight refetch was always hidden under the sync wait -> reverted.
//  - R4->R6 regression (11.65->13.9ms) persisted with sleep removed (R7):
//    the culprit is the 4B-entry layout making a block's 8-unit publish a
//    32B PARTIAL line SHARED with a neighbor block -> cross-XCD line
//    ping-pong at the MALL on the critical publish path every step.
//  Fixes:
//  - tbl[block][16 u32]: one exclusive 64B line per block, parity 0 in
//    words 0..7, parity 1 in words 8..15. Publish = 8 lanes, 32B, within
//    the block's own line. No line is ever written by two blocks.
//  - poll = ONE volatile global_load_dwordx4 (sc0 sc1 -> MALL-coherent)
//    per thread per sweep: thread tid polls units 4*tid..4*tid+3 living at
//    words (tid>>1)*16 + parity*8 + (tid&1)*4 (16B-aligned). 4x fewer poll
//    requests than R4, 2x fewer than R8 -> less MALL queueing. Per-dword
//    atomicity is sufficient: each u32 carries its own 2-LSB mantissa tag.
//  - tags unchanged (validated R6-R8): want = ((t+1)&3)^2; 0xAA poison
//    (tag 2) can only alias parity-1 want at t=3, but every parity-1 word
//    was genuinely overwritten at t=0 (tag 0) and t=2 (tag 2) first, and
//    same-address coherence is monotonic -> poison unreachable.
//  Kept: fast exp2 sigmoid/tanh tail, setprio(1) around tail, coalesced
//  out stores, conv precompute in LDS, hx_0 prestaged as zeros (no t=0 poll).

__device__ __forceinline__ float fast_sigmoid(float x) {
    float e = __builtin_amdgcn_exp2f(-1.44269504f * x);   // 2^(-x*log2e)
    return __builtin_amdgcn_rcpf(1.0f + e);
}

__global__ __launch_bounds__(NTHR, 2)
void qlstm_persistent(const float* __restrict__ inp,     // (S,1,4)
                      const float* __restrict__ conv_w,  // (4)
                      const float* __restrict__ conv_b,  // (1)
                      const float* __restrict__ Wg,      // (2049, 8192) row-major
                      const float* __restrict__ bg,      // (8192)
                      float* __restrict__ out,           // S*H + H + H
                      float* __restrict__ ws)            // scratch (poison 0xAA ok)
{
    const int b   = blockIdx.x;
    const int tid = threadIdx.x;
    const int l   = tid & 63;
    const int wv  = tid >> 6;

    u32* tbl = (u32*)ws;   // [NBLK][16]: exclusive 64B line per block

    __shared__ __align__(16) float hx_lds[HID];
    __shared__ __align__(16) float conv_lds[S_LEN];
    __shared__ float gates_lds[32];
    __shared__ float colw0[32];
    __shared__ float colb[32];

    // ---------------- init phase ----------------
    {
        const float cw0 = conv_w[0], cw1 = conv_w[1], cw2 = conv_w[2], cw3 = conv_w[3];
        const float cb  = conv_b[0];
        for (int g = tid; g < S_LEN; g += NTHR) {
            float4 x = ((const float4*)inp)[g];
            float v = x.x*cw0 + x.y*cw1 + x.z*cw2 + x.w*cw3 + cb;
            conv_lds[g] = fast_sigmoid(v);
        }
    }
    // hx_0 = 0 lives purely in LDS: step 0 needs no global exchange at all.
    ((float4*)hx_lds)[tid] = make_float4(0.f, 0.f, 0.f, 0.f);

    // this wave's 4 global column indices
    int jcol[4];
    #pragma unroll
    for (int c = 0; c < 4; ++c) {
        int cgi  = 4*wv + c;
        int gate = cgi >> 3;
        int mi   = cgi & 7;
        jcol[c]  = (gate << 11) + (b * 8 + mi);     // gate*2048 + m
    }
    if (l == 0) {
        #pragma unroll
        for (int c = 0; c < 4; ++c) {
            int cgi = 4*wv + c;
            colw0[cgi] = Wg[jcol[c]];               // row 0 = input (c_t) weight
            colb[cgi]  = bg[jcol[c]];
        }
    }

    // W registers (plain allocation; R8 proved residency doesn't matter):
    // wreg[c][4j+r] = W[1 + 4l + 256j + r][jcol[c]]
    float wreg[4][32];
    #pragma unroll
    for (int j = 0; j < 8; ++j)
        #pragma unroll
        for (int r = 0; r < 4; ++r) {
            const float* rowp = Wg + (size_t)(1 + 4*l + 256*j + r) * 8192;
            #pragma unroll
            for (int c = 0; c < 4; ++c)
                wreg[c][4*j + r] = rowp[jcol[c]];
        }

    float cx = 0.0f;                    // live only in lanes tid<8
    const int m_out = b * 8 + tid;      // hidden index for tid<8

    // thread tid polls units 4*tid..4*tid+3: block tid>>1, units (tid&1)*4+k
    const u32* poll_base = tbl + (tid >> 1) * 16 + (tid & 1) * 4;
    u32* pub_base = tbl + b * 16 + tid;      // + parity*8 at publish (tid<8)

    // ---------------- recurrence ----------------
    for (int t = 0; t < S_LEN; ++t) {
        if (t) {
            const u32 want = ((u32)(t + 1) & 3u) ^ 2u;
            const u32* pp = poll_base + ((t & 1) << 3);   // parity half-line
            u32x4 q;
            u32 miss;
            do {
                // one 16B MALL-coherent load per sweep; per-dword atomicity
                // is inherent, and each dword carries its own tag.
                asm volatile("global_load_dwordx4 %0, %1, off sc0 sc1\n\t"
                             "s_waitcnt vmcnt(0)"
                             : "=v"(q) : "v"(pp) : "memory");
                miss = ((q[0] ^ want) & 3u) | ((q[1] ^ want) & 3u)
                     | ((q[2] ^ want) & 3u) | ((q[3] ^ want) & 3u);
            } while (miss);
            u32x4 st;
            st[0] = q[0] & ~3u; st[1] = q[1] & ~3u;
            st[2] = q[2] & ~3u; st[3] = q[3] & ~3u;
            ((u32x4*)hx_lds)[tid] = st;     // units 4*tid..+3, ds_write_b128
        }
        __syncthreads();                    // A: hx_t staged

        // ---- 2048-MAC dot for this wave's 4 gate columns ----
        const float4* hl = (const float4*)hx_lds;
        float acc0 = 0.f, acc1 = 0.f, acc2 = 0.f, acc3 = 0.f;
        #pragma unroll
        for (int j = 0; j < 8; ++j) {
            float4 h = hl[l + 64*j];        // ds_read_b128, conflict-free
            acc0 = fmaf(h.x, wreg[0][4*j+0], acc0);
            acc1 = fmaf(h.x, wreg[1][4*j+0], acc1);
            acc2 = fmaf(h.x, wreg[2][4*j+0], acc2);
            acc3 = fmaf(h.x, wreg[3][4*j+0], acc3);
            acc0 = fmaf(h.y, wreg[0][4*j+1], acc0);
            acc1 = fmaf(h.y, wreg[1][4*j+1], acc1);
            acc2 = fmaf(h.y, wreg[2][4*j+1], acc2);
            acc3 = fmaf(h.y, wreg[3][4*j+1], acc3);
            acc0 = fmaf(h.z, wreg[0][4*j+2], acc0);
            acc1 = fmaf(h.z, wreg[1][4*j+2], acc1);
            acc2 = fmaf(h.z, wreg[2][4*j+2], acc2);
            acc3 = fmaf(h.z, wreg[3][4*j+2], acc3);
            acc0 = fmaf(h.w, wreg[0][4*j+3], acc0);
            acc1 = fmaf(h.w, wreg[1][4*j+3], acc1);
            acc2 = fmaf(h.w, wreg[2][4*j+3], acc2);
            acc3 = fmaf(h.w, wreg[3][4*j+3], acc3);
        }
        #pragma unroll
        for (int off = 32; off; off >>= 1) {
            acc0 += __shfl_down(acc0, off, 64);
            acc1 += __shfl_down(acc1, off, 64);
            acc2 += __shfl_down(acc2, off, 64);
            acc3 += __shfl_down(acc3, off, 64);
        }
        if (l == 0) {
            gates_lds[4*wv + 0] = acc0;
            gates_lds[4*wv + 1] = acc1;
            gates_lds[4*wv + 2] = acc2;
            gates_lds[4*wv + 3] = acc3;
        }
        __syncthreads();                    // B: gates complete

        if (wv == 0) __builtin_amdgcn_s_setprio(1);   // publisher outranks spinners
        if (tid < 8) {
            float ct = conv_lds[t];
            float fg = gates_lds[tid]      + ct*colw0[tid]      + colb[tid];
            float ig = gates_lds[8 + tid]  + ct*colw0[8 + tid]  + colb[8 + tid];
            float gg = gates_lds[16 + tid] + ct*colw0[16 + tid] + colb[16 + tid];
            float og = gates_lds[24 + tid] + ct*colw0[24 + tid] + colb[24 + tid];
            float f  = fast_sigmoid(fg);
            float ii = fast_sigmoid(ig);
            float gv = 2.0f * fast_sigmoid(2.0f * gg) - 1.0f;   // tanh
            float o  = fast_sigmoid(og);
            cx = f * cx + ii * gv;
            float hx = o * (2.0f * fast_sigmoid(2.0f * cx) - 1.0f);
            // publish hx_{t+1} into parity (t+1)&1 of the block's OWN line:
            // 8 lanes -> one 32B store, line never shared with another block.
            u32 word = (__float_as_uint(hx) & ~3u) | (((u32)(t + 2) & 3u) ^ 2u);
            __hip_atomic_store(pub_base + (((t + 1) & 1) << 3), word,
                               __ATOMIC_RELAXED, __HIP_MEMORY_SCOPE_AGENT);
            out[(size_t)t * HID + m_out] = hx;
            if (t == S_LEN - 1) {
                out[(size_t)S_LEN * HID + m_out]       = hx;   // final hx
                out[(size_t)S_LEN * HID + HID + m_out] = cx;   // final cx
            }
        }
        if (wv == 0) __builtin_amdgcn_s_setprio(0);
    }
}

extern "C" void kernel_launch(void* const* d_in, const int* in_sizes, int n_in,
                              void* d_out, int out_size, void* d_ws, size_t ws_size,
                              hipStream_t stream) {
    const float* inp    = (const float*)d_in[0];
    const float* conv_w = (const float*)d_in[1];
    const float* conv_b = (const float*)d_in[2];
    const float* Wg     = (const float*)d_in[3];
    const float* bg     = (const float*)d_in[4];
    float* out = (float*)d_out;
    float* ws  = (float*)d_ws;

    // no memset needed: poison tag (0xAA..&3 == 2) only aliases parity-1's
    // t=3 want, and every parity-1 word is overwritten at t=0 and t=2 first;
    // same-address coherence is monotonic, so poison is unreachable.
    void* args[] = {(void*)&inp, (void*)&conv_w, (void*)&conv_b,
                    (void*)&Wg, (void*)&bg, (void*)&out, (void*)&ws};
    hipLaunchCooperativeKernel((void*)qlstm_persistent,
                               dim3(NBLK), dim3(NTHR), args, 0, stream);
}